// Round 1
// baseline (878.187 us; speedup 1.0000x reference)
//
#include <hip/hip_runtime.h>

// ============================ shared arg struct ============================
struct Args {
  const float* x;
  const float* W[6];
  const float* b[6];
  const float* g[5];
  const float* be[5];
  float* out;
  unsigned* Bt1;            // [128 words][512 cols] layer-1 weight bits (transposed)
  unsigned* ByT;            // 5 x [16 words][512 cols]
  int* bs;                  // [6][512] bias signs (+1/-1)
  int* gs;                  // [5][512] col sums (int, exact)
  unsigned long long* gq;   // [5][512] col sumsq (u64, exact)
  unsigned* bar;            // barrier words: [0]=arrival count, [32]=generation
};

// ---- custom grid barrier: read-only polling, leader-only fences ----
// cg::grid_group::sync() polls its release flag with device-scope atomic RMWs:
// each poll writes a 64B line (rocprof: 748 MB WRITE_SIZE/dispatch) and the
// contended same-line RMWs from 8 XCDs convoy at one TCC (~120us/sync).
// This barrier: one fetch_add per block for arrival, spin on a SEPARATE
// cache line with relaxed agent-scope LOADS + s_sleep backoff. Epoch counter
// (target) is monotone within a dispatch; host memsets bar to 0 per launch.
__device__ __forceinline__ void gridbar(unsigned* bar, unsigned target)
{
  __syncthreads();                         // all block stores in local L2
  if (threadIdx.x == 0) {
    __threadfence();                       // release: write back dirty L2
    unsigned prev = __hip_atomic_fetch_add(&bar[0], 1u, __ATOMIC_RELAXED,
                                           __HIP_MEMORY_SCOPE_AGENT);
    if (prev == gridDim.x - 1) {           // last arriver
      __hip_atomic_store(&bar[0], 0u, __ATOMIC_RELAXED,
                         __HIP_MEMORY_SCOPE_AGENT);
      __hip_atomic_store(&bar[32], target, __ATOMIC_RELEASE,
                         __HIP_MEMORY_SCOPE_AGENT);
    } else {
      while (__hip_atomic_load(&bar[32], __ATOMIC_RELAXED,
                               __HIP_MEMORY_SCOPE_AGENT) < target)
        __builtin_amdgcn_s_sleep(32);      // ~0.85us poll period, read-only
    }
    __threadfence();                       // acquire: invalidate stale L2
  }
  __syncthreads();
}

// ===================== PRIMARY: one cooperative kernel =====================
// 512 blocks x 256 thr, 32 rows/block resident for the whole net. Thread
// (wave wv, lane) holds y[r][jj] = row row0+wv*8+r, col jj*64+lane in regs.
// A-bits via in-wave __ballot (wave-uniform); B bits staged in 16KB LDS
// chunks ([word][col]: bank = col%32, 2-way = free). Exact-int BN stats.
__global__ __launch_bounds__(256, 2) void bnn_all(Args a)
{
  __shared__ __align__(16) unsigned Bsw[8 * 512];    // 16 KB
  __shared__ __align__(16) float thrbuf[1536];       // 6 KB; aliased by red_s/red_q
  int* red_s = (int*)thrbuf;
  int* red_q = red_s + 512;

  const int tid = threadIdx.x;
  const int lane = tid & 63;
  const int wv = tid >> 6;
  const int row0 = blockIdx.x * 32;
  int ep = 0;                              // barrier epoch (uniform control flow)

  // ---------- phase 0: zero stats + pack weight/bias sign bits ----------
  {
    int idx = blockIdx.x * 256 + tid;
    if (idx < 7680) ((int*)a.gs)[idx] = 0;   // gs(10240B)+gq(20480B) contiguous
  }
  for (int R = blockIdx.x; R < 1885; R += 512) {
    int l, n;
    if      (R < 500)  { l = 0; n = R; }
    else if (R < 900)  { l = 1; n = R - 500; }
    else if (R < 1250) { l = 2; n = R - 900; }
    else if (R < 1550) { l = 3; n = R - 1250; }
    else if (R < 1850) { l = 4; n = R - 1550; }
    else               { l = 5; n = R - 1850; }
    const int Ks[6] = {4096, 500, 400, 350, 300, 300};
    int K = Ks[l];
    int chunks = (l == 0) ? 64 : 8;
    unsigned* Bout = (l == 0) ? a.Bt1 : (a.ByT + (size_t)(l - 1) * 16 * 512);
    const float* Wrow = a.W[l] + (size_t)n * K;
    for (int c = wv; c < chunks; c += 4) {
      int k = c * 64 + lane;
      bool pred = (k < K) && (Wrow[k] >= 0.0f);
      unsigned long long m = __ballot(pred);
      if (lane == 0) {
        Bout[(size_t)(2 * c) * 512 + n]     = (unsigned)m;
        Bout[(size_t)(2 * c + 1) * 512 + n] = (unsigned)(m >> 32);
      }
    }
    if (tid == 0) a.bs[l * 512 + n] = (a.b[l][n] >= 0.0f) ? 1 : -1;
  }
  gridbar(a.bar, ++ep);

  // ---------- layer 1: x read once -> y[8][8] registers ----------
  int y[8][8];
#pragma unroll
  for (int r = 0; r < 8; r++)
#pragma unroll
    for (int j = 0; j < 8; j++) y[r][j] = 0;

  for (int kc = 0; kc < 16; kc++) {          // 16 chunks of 256 K-bits (8 words)
    __syncthreads();                         // Bsw reuse guard
    const uint4* src = (const uint4*)(a.Bt1 + kc * 4096);
#pragma unroll
    for (int i = 0; i < 4; i++)
      ((uint4*)Bsw)[i * 256 + tid] = src[i * 256 + tid];
    unsigned Aw[8][8];
#pragma unroll
    for (int r = 0; r < 8; r++) {
      const float* xp = a.x + (size_t)(row0 + wv * 8 + r) * 4096 + kc * 256 + lane;
      float xv[4];
#pragma unroll
      for (int cb = 0; cb < 4; cb++) xv[cb] = xp[cb * 64];
#pragma unroll
      for (int cb = 0; cb < 4; cb++) {
        unsigned long long m = __ballot(xv[cb] >= 0.0f);
        Aw[r][2 * cb]     = (unsigned)m;
        Aw[r][2 * cb + 1] = (unsigned)(m >> 32);
      }
    }
    __syncthreads();
#pragma unroll
    for (int w = 0; w < 8; w++) {
#pragma unroll
      for (int jj = 0; jj < 8; jj++) {
        unsigned bw = Bsw[(w << 9) + (jj << 6) + lane];
#pragma unroll
        for (int r = 0; r < 8; r++)
          y[r][jj] += __popc(Aw[r][w] ^ bw);
      }
    }
  }
#pragma unroll
  for (int jj = 0; jj < 8; jj++) {
    int col = (jj << 6) + lane;
    int bsv = (col < 500) ? a.bs[col] : 0;
#pragma unroll
    for (int r = 0; r < 8; r++) y[r][jj] = 4096 - 2 * y[r][jj] + bsv;
  }
  // layer-1 stats (slot 0)
  {
    __syncthreads();
    red_s[tid] = 0; red_s[tid + 256] = 0;
    red_q[tid] = 0; red_q[tid + 256] = 0;
    __syncthreads();
#pragma unroll
    for (int jj = 0; jj < 8; jj++) {
      int col = (jj << 6) + lane;
      if (col < 500) {
        int s = 0, q = 0;
#pragma unroll
        for (int r = 0; r < 8; r++) { s += y[r][jj]; q += y[r][jj] * y[r][jj]; }
        atomicAdd(&red_s[col], s);
        atomicAdd(&red_q[col], q);   // per-block <= 32*4097^2 < 2^31
      }
    }
    __syncthreads();
    for (int c = tid; c < 500; c += 256) {
      atomicAdd(&a.gs[c], red_s[c]);
      atomicAdd(&a.gq[c], (unsigned long long)(long long)red_q[c]);
    }
    gridbar(a.bar, ++ep);
  }

  // ---------- layers 2..6 ----------
  const int Kins[5]  = {500, 400, 350, 300, 300};
  const int Nouts[5] = {400, 350, 300, 300, 35};
#pragma unroll 1
  for (int li = 1; li <= 5; li++) {
    const int Kin  = Kins[li - 1];
    const int Nout = Nouts[li - 1];
    const bool final_layer = (li == 5);
    const int* gs_in = a.gs + (size_t)(li - 1) * 512;
    const unsigned long long* gq_in = a.gq + (size_t)(li - 1) * 512;
    const unsigned* Bl = a.ByT + (size_t)(li - 1) * 16 * 512;
    const int* bsl = a.bs + (size_t)li * 512;

    __syncthreads();   // prev epilogue LDS reads done before thrbuf rewrite
    for (int k = tid; k < 512; k += 256) {
      float t = 0.f, sg = 0.f, cc = -1.f;
      if (k < Kin) {
        float m  = (float)gs_in[k] * (1.0f / 16384.0f);
        float ms = (float)gq_in[k] * (1.0f / 16384.0f);
        float var = fmaxf(ms - m * m, 0.0f);
        float gv = a.g[li - 1][k], be = a.be[li - 1][k];
        if (gv != 0.0f) {
          t = m - be * sqrtf(var + 1e-5f) / gv;
          sg = (gv > 0.0f) ? 1.0f : -1.0f;
          cc = 0.0f;
        } else { t = 0.0f; sg = 0.0f; cc = be; }
      }
      thrbuf[k] = t; thrbuf[512 + k] = sg; thrbuf[1024 + k] = cc;
    }

    int nacc[8][8];
#pragma unroll
    for (int r = 0; r < 8; r++)
#pragma unroll
      for (int j = 0; j < 8; j++) nacc[r][j] = 0;

    for (int c2 = 0; c2 < 2; c2++) {
      __syncthreads();   // thr visible (c2=0) / Bsw reuse (c2=1)
      const uint4* src = (const uint4*)(Bl + c2 * 4096);
#pragma unroll
      for (int i = 0; i < 4; i++)
        ((uint4*)Bsw)[i * 256 + tid] = src[i * 256 + tid];
      unsigned Aw[8][8];
#pragma unroll
      for (int cb = 0; cb < 4; cb++) {
        int k = c2 * 256 + (cb << 6) + lane;
        float t = thrbuf[k], sg = thrbuf[512 + k], cc = thrbuf[1024 + k];
#pragma unroll
        for (int r = 0; r < 8; r++) {
          bool p = (k < Kin) &&
                   ((((float)y[r][c2 * 4 + cb] - t) * sg + cc) >= 0.0f);
          unsigned long long m = __ballot(p);
          Aw[r][2 * cb]     = (unsigned)m;
          Aw[r][2 * cb + 1] = (unsigned)(m >> 32);
        }
      }
      __syncthreads();
#pragma unroll
      for (int w = 0; w < 8; w++) {
#pragma unroll
        for (int jj = 0; jj < 8; jj++) {
          unsigned bw = Bsw[(w << 9) + (jj << 6) + lane];
#pragma unroll
          for (int r = 0; r < 8; r++)
            nacc[r][jj] += __popc(Aw[r][w] ^ bw);
        }
      }
    }
#pragma unroll
    for (int jj = 0; jj < 8; jj++) {
      int col = (jj << 6) + lane;
      int bsv = (col < Nout) ? bsl[col] : 0;
#pragma unroll
      for (int r = 0; r < 8; r++) {
        int v = Kin - 2 * nacc[r][jj] + bsv;
        y[r][jj] = v;
        if (final_layer && col < 35)
          a.out[(size_t)(row0 + wv * 8 + r) * 35 + col] = (float)v;
      }
    }
    if (!final_layer) {
      int* gs_out = a.gs + (size_t)li * 512;
      unsigned long long* gq_out = a.gq + (size_t)li * 512;
      __syncthreads();
      red_s[tid] = 0; red_s[tid + 256] = 0;
      red_q[tid] = 0; red_q[tid + 256] = 0;
      __syncthreads();
#pragma unroll
      for (int jj = 0; jj < 8; jj++) {
        int col = (jj << 6) + lane;
        if (col < Nout) {
          int s = 0, q = 0;
#pragma unroll
          for (int r = 0; r < 8; r++) { s += y[r][jj]; q += y[r][jj] * y[r][jj]; }
          atomicAdd(&red_s[col], s);
          atomicAdd(&red_q[col], q);
        }
      }
      __syncthreads();
      for (int c = tid; c < Nout; c += 256) {
        atomicAdd(&gs_out[c], red_s[c]);
        atomicAdd(&gq_out[c], (unsigned long long)(long long)red_q[c]);
      }
      gridbar(a.bar, ++ep);
    }
  }
}

// ===================== FALLBACK: proven round-1 pipeline =====================
struct PackArgs { const float* W[6]; const float* b[6]; };

__global__ __launch_bounds__(256) void fb_pack(PackArgs a, unsigned* B1, unsigned* By, int* bs)
{
  int blk = blockIdx.x;
  int l, n;
  if      (blk < 500)  { l = 0; n = blk; }
  else if (blk < 900)  { l = 1; n = blk - 500; }
  else if (blk < 1250) { l = 2; n = blk - 900; }
  else if (blk < 1550) { l = 3; n = blk - 1250; }
  else if (blk < 1850) { l = 4; n = blk - 1550; }
  else                 { l = 5; n = blk - 1850; }
  const int Ks[6] = {4096, 500, 400, 350, 300, 300};
  int K = Ks[l];
  int KW = (l == 0) ? 128 : 16;
  unsigned* Bout = (l == 0) ? B1 : (By + (size_t)(l - 1) * 512 * 16);
  const float* Wrow = a.W[l] + (size_t)n * K;
  int lane = threadIdx.x & 63;
  int wvv = threadIdx.x >> 6;
  for (int c = wvv; c < KW / 2; c += 4) {
    int k = c * 64 + lane;
    bool pred = (k < K) && (Wrow[k] >= 0.0f);
    unsigned long long m = __ballot(pred);
    if (lane == 0) {
      Bout[(size_t)n * KW + 2 * c]     = (unsigned)m;
      Bout[(size_t)n * KW + 2 * c + 1] = (unsigned)(m >> 32);
    }
  }
  if (threadIdx.x == 0) bs[l * 512 + n] = (a.b[l][n] >= 0.0f) ? 1 : -1;
}

__global__ __launch_bounds__(256) void fb_gemm1(const float* __restrict__ x,
    const unsigned* __restrict__ B1, const int* __restrict__ bs1,
    short* __restrict__ y1, int* __restrict__ gs, unsigned long long* __restrict__ gq)
{
  __shared__ __align__(16) unsigned Abits[32 * 128];
  __shared__ __align__(16) unsigned Bsw[256 * 32];
  __shared__ int red_s[256];
  __shared__ int red_q[256];
  int tid = threadIdx.x;
  int lane = tid & 63, wvv = tid >> 6;
  int cg2 = tid & 31, rg = tid >> 5;
  int row0 = blockIdx.x * 32;

  for (int i0 = wvv * 512; i0 < wvv * 512 + 512; i0 += 8) {
    int r = i0 >> 6;
    int cb = i0 & 63;
    const float* xp = x + (size_t)(row0 + r) * 4096 + cb * 64 + lane;
    float v[8];
#pragma unroll
    for (int u = 0; u < 8; u++) v[u] = xp[u * 64];
#pragma unroll
    for (int u = 0; u < 8; u++) {
      unsigned long long m = __ballot(v[u] >= 0.0f);
      if (lane == 0)
        *(unsigned long long*)&Abits[r * 128 + 2 * (cb + u)] = m;
    }
  }

  for (int pass = 0; pass < 2; pass++) {
    int colbase = pass * 256;
    unsigned acc[4][8];
#pragma unroll
    for (int r = 0; r < 4; r++)
#pragma unroll
      for (int j = 0; j < 8; j++) acc[r][j] = 0;

    for (int kc = 0; kc < 4; kc++) {
      __syncthreads();
#pragma unroll
      for (int i = 0; i < 8; i++) {
        int q = i * 256 + tid;
        int c = q >> 3;
        int w4 = (q & 7) << 2;
        uint4 bv = *(const uint4*)(B1 + (size_t)(colbase + c) * 128 + kc * 32 + w4);
        int g = (w4 >> 2) ^ (c & 7);
        *(uint4*)&Bsw[c * 32 + 4 * g] = bv;
      }
      __syncthreads();
#pragma unroll
      for (int w4 = 0; w4 < 32; w4 += 4) {
        uint4 av[4];
#pragma unroll
        for (int r = 0; r < 4; r++)
          av[r] = *(const uint4*)&Abits[(rg * 4 + r) * 128 + kc * 32 + w4];
#pragma unroll
        for (int jj = 0; jj < 8; jj++) {
          int c = jj * 32 + cg2;
          int g = (w4 >> 2) ^ (c & 7);
          uint4 bv = *(const uint4*)&Bsw[c * 32 + 4 * g];
#pragma unroll
          for (int r = 0; r < 4; r++)
            acc[r][jj] += __popc(av[r].x ^ bv.x) + __popc(av[r].y ^ bv.y)
                        + __popc(av[r].z ^ bv.z) + __popc(av[r].w ^ bv.w);
        }
      }
    }
    red_s[tid] = 0; red_q[tid] = 0;
    __syncthreads();
#pragma unroll
    for (int jj = 0; jj < 8; jj++) {
      int col = colbase + jj * 32 + cg2;
      int bsv = (col < 500) ? bs1[col] : 0;
      int s = 0, q = 0;
#pragma unroll
      for (int r = 0; r < 4; r++) {
        int yv = 4096 - 2 * (int)acc[r][jj] + bsv;
        if (col < 500)
          y1[(size_t)(row0 + rg * 4 + r) * 500 + col] = (short)yv;
        s += yv; q += yv * yv;
      }
      atomicAdd(&red_s[jj * 32 + cg2], s);
      atomicAdd(&red_q[jj * 32 + cg2], q);
    }
    __syncthreads();
    {
      int col = colbase + tid;
      if (col < 500) {
        atomicAdd(&gs[col], red_s[tid]);
        atomicAdd(&gq[col], (unsigned long long)(long long)red_q[tid]);
      }
    }
  }
}

__global__ __launch_bounds__(256) void fb_gemmy(
    const short* __restrict__ yin, int strin, int Kin,
    const int* __restrict__ gs_in, const unsigned long long* __restrict__ gq_in,
    const float* __restrict__ g_in, const float* __restrict__ be_in,
    const unsigned* __restrict__ Bb, const int* __restrict__ bsl,
    int Nout, int strout, int passes,
    short* __restrict__ yout, int* __restrict__ gs_out, unsigned long long* __restrict__ gq_out,
    float* __restrict__ fout, int is_final)
{
  __shared__ __align__(16) unsigned Abits[32 * 16];
  __shared__ __align__(16) unsigned Bsw[256 * 16];
  __shared__ float thr_t[512], thr_g[512], thr_c[512];
  __shared__ int red_s[256], red_q[256];
  int tid = threadIdx.x;
  int lane = tid & 63, wvv = tid >> 6;
  int cg2 = tid & 31, rg = tid >> 5;
  int row0 = blockIdx.x * 32;

  for (int k = tid; k < 512; k += 256) {
    float t = 0.f, sg = 0.f, cc = -1.f;
    if (k < Kin) {
      float m  = (float)gs_in[k] * (1.0f / 16384.0f);
      float ms = (float)gq_in[k] * (1.0f / 16384.0f);
      float var = fmaxf(ms - m * m, 0.0f);
      float g = g_in[k], be = be_in[k];
      if (g != 0.0f) {
        t = m - be * sqrtf(var + 1e-5f) / g;
        sg = (g > 0.0f) ? 1.0f : -1.0f;
        cc = 0.0f;
      } else { t = 0.0f; sg = 0.0f; cc = be; }
    }
    thr_t[k] = t; thr_g[k] = sg; thr_c[k] = cc;
  }
  __syncthreads();

  for (int i0 = wvv * 64; i0 < wvv * 64 + 64; i0 += 4) {
    int r = i0 >> 3;
    int cb = i0 & 7;
    const short* yp = yin + (size_t)(row0 + r) * strin;
    float v[4];
#pragma unroll
    for (int u = 0; u < 4; u++) {
      int k = (cb + u) * 64 + lane;
      v[u] = (k < Kin) ? (float)yp[k] : -1.0f;
    }
#pragma unroll
    for (int u = 0; u < 4; u++) {
      int k = (cb + u) * 64 + lane;
      bool p = (k < Kin) && (((v[u] - thr_t[k]) * thr_g[k] + thr_c[k]) >= 0.0f);
      unsigned long long m = __ballot(p);
      if (lane == 0)
        *(unsigned long long*)&Abits[r * 16 + 2 * (cb + u)] = m;
    }
  }

  for (int pass = 0; pass < passes; pass++) {
    int colbase = pass * 256;
    __syncthreads();
#pragma unroll
    for (int i = 0; i < 4; i++) {
      int q = i * 256 + tid;
      int c = q >> 2;
      int w4 = (q & 3) << 2;
      uint4 bv = *(const uint4*)(Bb + (size_t)(colbase + c) * 16 + w4);
      int g = (w4 >> 2) ^ (c & 3);
      *(uint4*)&Bsw[c * 16 + 4 * g] = bv;
    }
    __syncthreads();
    unsigned acc[4][8];
#pragma unroll
    for (int r = 0; r < 4; r++)
#pragma unroll
      for (int j = 0; j < 8; j++) acc[r][j] = 0;
#pragma unroll
    for (int w4 = 0; w4 < 4; w4++) {
      uint4 av[4];
#pragma unroll
      for (int r = 0; r < 4; r++)
        av[r] = *(const uint4*)&Abits[(rg * 4 + r) * 16 + w4 * 4];
#pragma unroll
      for (int jj = 0; jj < 8; jj++) {
        int c = jj * 32 + cg2;
        int g = (w4) ^ (c & 3);
        uint4 bv = *(const uint4*)&Bsw[c * 16 + 4 * g];
#pragma unroll
        for (int r = 0; r < 4; r++)
          acc[r][jj] += __popc(av[r].x ^ bv.x) + __popc(av[r].y ^ bv.y)
                      + __popc(av[r].z ^ bv.z) + __popc(av[r].w ^ bv.w);
      }
    }
    red_s[tid] = 0; red_q[tid] = 0;
    __syncthreads();
#pragma unroll
    for (int jj = 0; jj < 8; jj++) {
      int col = colbase + jj * 32 + cg2;
      int bsv = (col < Nout) ? bsl[col] : 0;
      int s = 0, q = 0;
#pragma unroll
      for (int r = 0; r < 4; r++) {
        int yv = Kin - 2 * (int)acc[r][jj] + bsv;
        if (col < Nout) {
          if (is_final) fout[(size_t)(row0 + rg * 4 + r) * Nout + col] = (float)yv;
          else          yout[(size_t)(row0 + rg * 4 + r) * strout + col] = (short)yv;
        }
        s += yv; q += yv * yv;
      }
      if (!is_final && col < Nout) {
        atomicAdd(&red_s[jj * 32 + cg2], s);
        atomicAdd(&red_q[jj * 32 + cg2], q);
      }
    }
    if (!is_final) {
      __syncthreads();
      int col = colbase + tid;
      if (col < Nout) {
        atomicAdd(&gs_out[col], red_s[tid]);
        atomicAdd(&gq_out[col], (unsigned long long)(long long)red_q[tid]);
      }
      __syncthreads();
    }
  }
}

// ================================ host ================================
extern "C" void kernel_launch(void* const* d_in, const int* in_sizes, int n_in,
                              void* d_out, int out_size, void* d_ws, size_t ws_size,
                              hipStream_t stream)
{
  (void)in_sizes; (void)n_in; (void)out_size; (void)ws_size;
  char* ws = (char*)d_ws;
  unsigned* Bt1 = (unsigned*)(ws);
  unsigned* ByT = (unsigned*)(ws + 262144);
  int* bs       = (int*)(ws + 425984);
  int* gs       = (int*)(ws + 438272);
  unsigned long long* gq = (unsigned long long*)(ws + 448512);
  unsigned* bar = (unsigned*)(ws + 469504);   // 2 cache lines: count / gen
  short* yA = (short*)(ws + 471040);
  short* yB = yA + (size_t)16384 * 512;

  Args ka;
  ka.x    = (const float*)d_in[0];
  ka.W[0] = (const float*)d_in[1];  ka.b[0] = (const float*)d_in[2];
  ka.W[1] = (const float*)d_in[5];  ka.b[1] = (const float*)d_in[6];
  ka.W[2] = (const float*)d_in[9];  ka.b[2] = (const float*)d_in[10];
  ka.W[3] = (const float*)d_in[13]; ka.b[3] = (const float*)d_in[14];
  ka.W[4] = (const float*)d_in[17]; ka.b[4] = (const float*)d_in[18];
  ka.W[5] = (const float*)d_in[21]; ka.b[5] = (const float*)d_in[22];
  ka.g[0] = (const float*)d_in[3];  ka.be[0] = (const float*)d_in[4];
  ka.g[1] = (const float*)d_in[7];  ka.be[1] = (const float*)d_in[8];
  ka.g[2] = (const float*)d_in[11]; ka.be[2] = (const float*)d_in[12];
  ka.g[3] = (const float*)d_in[15]; ka.be[3] = (const float*)d_in[16];
  ka.g[4] = (const float*)d_in[19]; ka.be[4] = (const float*)d_in[20];
  ka.out = (float*)d_out;
  ka.Bt1 = Bt1; ka.ByT = ByT; ka.bs = bs; ka.gs = gs; ka.gq = gq;
  ka.bar = bar;

  // Env-constant gate: can 512 blocks (2/CU on 256 CUs) be co-resident?
  int maxPerCU = 0;
  hipError_t qerr = hipOccupancyMaxActiveBlocksPerMultiprocessor(
      &maxPerCU, reinterpret_cast<const void*>(&bnn_all), 256, 0);
  bool use_coop = (qerr == hipSuccess) && (maxPerCU >= 2);

  if (use_coop) {
    hipMemsetAsync(ws + 469504, 0, 256, stream);   // barrier count + gen = 0
    void* args_arr[] = { &ka };
    hipLaunchCooperativeKernel(reinterpret_cast<void*>(&bnn_all),
                               dim3(512), dim3(256), args_arr, 0, stream);
    return;
  }

  // -------- fallback: proven multi-kernel pipeline (round-1 structure) --------
  hipMemsetAsync(ws + 438272, 0, 30720, stream);  // zero stats

  PackArgs pa;
  for (int i = 0; i < 6; i++) { pa.W[i] = ka.W[i]; pa.b[i] = ka.b[i]; }

  fb_pack<<<1885, 256, 0, stream>>>(pa, Bt1, ByT, bs);
  fb_gemm1<<<512, 256, 0, stream>>>((const float*)d_in[0], Bt1, bs, yA, gs, gq);
  fb_gemmy<<<512, 256, 0, stream>>>(yA, 500, 500, gs, gq,
      ka.g[0], ka.be[0], ByT + 0 * 512 * 16, bs + 512, 400, 400, 2,
      yB, gs + 512, gq + 512, nullptr, 0);
  fb_gemmy<<<512, 256, 0, stream>>>(yB, 400, 400, gs + 512, gq + 512,
      ka.g[1], ka.be[1], ByT + 1 * 512 * 16, bs + 1024, 350, 352, 2,
      yA, gs + 1024, gq + 1024, nullptr, 0);
  fb_gemmy<<<512, 256, 0, stream>>>(yA, 352, 350, gs + 1024, gq + 1024,
      ka.g[2], ka.be[2], ByT + 2 * 512 * 16, bs + 1536, 300, 300, 2,
      yB, gs + 1536, gq + 1536, nullptr, 0);
  fb_gemmy<<<512, 256, 0, stream>>>(yB, 300, 300, gs + 1536, gq + 1536,
      ka.g[3], ka.be[3], ByT + 3 * 512 * 16, bs + 2048, 300, 300, 2,
      yA, gs + 2048, gq + 2048, nullptr, 0);
  fb_gemmy<<<512, 256, 0, stream>>>(yA, 300, 300, gs + 2048, gq + 2048,
      ka.g[4], ka.be[4], ByT + 4 * 512 * 16, bs + 2560, 35, 35, 1,
      nullptr, nullptr, nullptr, (float*)d_out, 1);
}

// Round 2
// 875.789 us; speedup vs baseline: 1.0027x; 1.0027x over previous
//
#include <hip/hip_runtime.h>

// ============================ shared arg struct ============================
struct Args {
  const float* x;
  const float* W[6];
  const float* b[6];
  const float* g[5];
  const float* be[5];
  float* out;
  unsigned* Bt1;            // [128 words][512 cols] layer-1 weight bits (transposed)
  unsigned* ByT;            // 5 x [16 words][512 cols]
  int* bs;                  // [6][512] bias signs (+1/-1)
  int* gs;                  // [5][512] col sums (int, exact)
  unsigned long long* gq;   // [5][512] col sumsq (u64, exact)
  unsigned* bar;            // barrier words: [0]=arrival count, [32]=generation
};

// ---- custom grid barrier: read-only polling, leader-only fences ----
// Arrival: one agent-scope fetch_add per block. Wait: read-only agent-scope
// polling of a generation word on a separate cache line + s_sleep backoff.
// Requires all blocks co-resident (gated by hipOccupancyMaxActiveBlocks...);
// does NOT require cooperative launch. Host memsets bar to 0 per launch.
__device__ __forceinline__ void gridbar(unsigned* bar, unsigned target)
{
  __syncthreads();                         // all block work done
  if (threadIdx.x == 0) {
    __threadfence();                       // release: write back dirty L2
    unsigned prev = __hip_atomic_fetch_add(&bar[0], 1u, __ATOMIC_RELAXED,
                                           __HIP_MEMORY_SCOPE_AGENT);
    if (prev == gridDim.x - 1) {           // last arriver
      __hip_atomic_store(&bar[0], 0u, __ATOMIC_RELAXED,
                         __HIP_MEMORY_SCOPE_AGENT);
      __hip_atomic_store(&bar[32], target, __ATOMIC_RELEASE,
                         __HIP_MEMORY_SCOPE_AGENT);
    } else {
      while (__hip_atomic_load(&bar[32], __ATOMIC_RELAXED,
                               __HIP_MEMORY_SCOPE_AGENT) < target)
        __builtin_amdgcn_s_sleep(2);       // ~0.1us poll period, read-only
    }
    __threadfence();                       // acquire: invalidate stale L2
  }
  __syncthreads();
}

// ===================== PRIMARY: one persistent-grid kernel =====================
// 1024 blocks x 256 thr (4/CU, 16 waves/CU), 16 rows/block resident for the
// whole net. Thread (wave wv, lane) holds y[r][jj] = row row0+wv*4+r, col
// jj*64+lane in regs. Layer 1 software-pipelined: x chunk kc+1 prefetched into
// regs during popc of chunk kc; B tiles double-buffered in 32KB LDS with ONE
// __syncthreads per chunk (stage-loads early, ds_writes after popc). Exact-int
// BN stats; custom read-only-spin grid barrier (6 barriers total).
__global__ __launch_bounds__(256, 4) void bnn_all(Args a)
{
  __shared__ __align__(16) unsigned Bsw[16 * 512];   // 32 KB: L1 dbuf / whole ByT layer
  __shared__ __align__(16) float thrbuf[1536];       // 6 KB; aliased by red_s/red_q
  int* red_s = (int*)thrbuf;
  int* red_q = red_s + 512;

  const int tid = threadIdx.x;
  const int lane = tid & 63;
  const int wv = tid >> 6;
  const int row0 = blockIdx.x * 16;
  int ep = 0;                              // barrier epoch (uniform control flow)

  // ---------- phase 0: zero stats + pack weight/bias sign bits ----------
  {
    int idx = blockIdx.x * 256 + tid;
    if (idx < 7680) ((int*)a.gs)[idx] = 0;   // gs(10240B)+gq(20480B) contiguous
  }
  for (int R = blockIdx.x; R < 1885; R += gridDim.x) {
    int l, n;
    if      (R < 500)  { l = 0; n = R; }
    else if (R < 900)  { l = 1; n = R - 500; }
    else if (R < 1250) { l = 2; n = R - 900; }
    else if (R < 1550) { l = 3; n = R - 1250; }
    else if (R < 1850) { l = 4; n = R - 1550; }
    else               { l = 5; n = R - 1850; }
    const int Ks[6] = {4096, 500, 400, 350, 300, 300};
    int K = Ks[l];
    int chunks = (l == 0) ? 64 : 8;
    unsigned* Bout = (l == 0) ? a.Bt1 : (a.ByT + (size_t)(l - 1) * 16 * 512);
    const float* Wrow = a.W[l] + (size_t)n * K;
    for (int c = wv; c < chunks; c += 4) {
      int k = c * 64 + lane;
      bool pred = (k < K) && (Wrow[k] >= 0.0f);
      unsigned long long m = __ballot(pred);
      if (lane == 0) {
        Bout[(size_t)(2 * c) * 512 + n]     = (unsigned)m;
        Bout[(size_t)(2 * c + 1) * 512 + n] = (unsigned)(m >> 32);
      }
    }
    if (tid == 0) a.bs[l * 512 + n] = (a.b[l][n] >= 0.0f) ? 1 : -1;
  }

  // prefetch x chunk kc=0 into regs BEFORE the barrier (hides under barrier wait)
  const float* xbase = a.x + (size_t)(row0 + wv * 4) * 4096 + lane;
  float xv[4][4];
#pragma unroll
  for (int r = 0; r < 4; r++)
#pragma unroll
    for (int cb = 0; cb < 4; cb++)
      xv[r][cb] = xbase[(size_t)r * 4096 + cb * 64];

  gridbar(a.bar, ++ep);

  // ---------- layer 1: x read once -> y[4][8] registers ----------
  // prologue: stage B chunk 0 into buf0
  {
    const uint4* src = (const uint4*)a.Bt1;
#pragma unroll
    for (int i = 0; i < 4; i++)
      ((uint4*)Bsw)[i * 256 + tid] = src[i * 256 + tid];
  }

  int y[4][8];
#pragma unroll
  for (int r = 0; r < 4; r++)
#pragma unroll
    for (int j = 0; j < 8; j++) y[r][j] = 0;

  for (int kc = 0; kc < 16; kc++) {        // 16 chunks of 256 K-bits (8 words)
    // ballots from prefetched xv (no LDS, no waits beyond vmcnt of prefetch)
    unsigned Aw[4][8];
#pragma unroll
    for (int r = 0; r < 4; r++)
#pragma unroll
      for (int cb = 0; cb < 4; cb++) {
        unsigned long long m = __ballot(xv[r][cb] >= 0.0f);
        Aw[r][2 * cb]     = (unsigned)m;
        Aw[r][2 * cb + 1] = (unsigned)(m >> 32);
      }
    // prefetch x chunk kc+1 (WAR on xv: issued after ballots consume regs)
    if (kc < 15) {
#pragma unroll
      for (int r = 0; r < 4; r++)
#pragma unroll
        for (int cb = 0; cb < 4; cb++)
          xv[r][cb] = xbase[(size_t)r * 4096 + (kc + 1) * 256 + cb * 64];
    }
    __syncthreads();   // buf[kc&1] staged (prev iter's post-sync writes) & prev popc done
    // stage-loads for kc+1 issue now; ds_writes deferred to after popc (T14)
    uint4 sbuf[4];
    if (kc < 15) {
      const uint4* src = (const uint4*)(a.Bt1 + (size_t)(kc + 1) * 4096);
#pragma unroll
      for (int i = 0; i < 4; i++) sbuf[i] = src[i * 256 + tid];
    }
    const unsigned* B = Bsw + (kc & 1) * 4096;
#pragma unroll
    for (int w = 0; w < 8; w++) {
#pragma unroll
      for (int jj = 0; jj < 8; jj++) {
        unsigned bw = B[(w << 9) + (jj << 6) + lane];
#pragma unroll
        for (int r = 0; r < 4; r++)
          y[r][jj] += __popc(Aw[r][w] ^ bw);
      }
    }
    if (kc < 15) {
      uint4* dst = (uint4*)Bsw + (size_t)((kc + 1) & 1) * 1024;
#pragma unroll
      for (int i = 0; i < 4; i++) dst[i * 256 + tid] = sbuf[i];
    }
  }
#pragma unroll
  for (int jj = 0; jj < 8; jj++) {
    int col = (jj << 6) + lane;
    int bsv = (col < 500) ? a.bs[col] : 0;
#pragma unroll
    for (int r = 0; r < 4; r++) y[r][jj] = 4096 - 2 * y[r][jj] + bsv;
  }
  // layer-1 stats (slot 0)
  {
    __syncthreads();
    red_s[tid] = 0; red_s[tid + 256] = 0;
    red_q[tid] = 0; red_q[tid + 256] = 0;
    __syncthreads();
#pragma unroll
    for (int jj = 0; jj < 8; jj++) {
      int col = (jj << 6) + lane;
      if (col < 500) {
        int s = 0, q = 0;
#pragma unroll
        for (int r = 0; r < 4; r++) { s += y[r][jj]; q += y[r][jj] * y[r][jj]; }
        atomicAdd(&red_s[col], s);
        atomicAdd(&red_q[col], q);   // per-block <= 16*4097^2 < 2^31
      }
    }
    __syncthreads();
    for (int c = tid; c < 500; c += 256) {
      atomicAdd(&a.gs[c], red_s[c]);
      atomicAdd(&a.gq[c], (unsigned long long)(long long)red_q[c]);
    }
    gridbar(a.bar, ++ep);
  }

  // ---------- layers 2..6 ----------
  const int Kins[5]  = {500, 400, 350, 300, 300};
  const int Nouts[5] = {400, 350, 300, 300, 35};
#pragma unroll 1
  for (int li = 1; li <= 5; li++) {
    const int Kin  = Kins[li - 1];
    const int Nout = Nouts[li - 1];
    const bool final_layer = (li == 5);
    const int* gs_in = a.gs + (size_t)(li - 1) * 512;
    const unsigned long long* gq_in = a.gq + (size_t)(li - 1) * 512;
    const unsigned* Bl = a.ByT + (size_t)(li - 1) * 16 * 512;
    const int* bsl = a.bs + (size_t)li * 512;

    __syncthreads();   // prev epilogue LDS reads done before thrbuf/Bsw rewrite
    // stage whole 32KB B-slice: loads issue now, overlap the BN-threshold math
    uint4 bv[8];
#pragma unroll
    for (int i = 0; i < 8; i++) bv[i] = ((const uint4*)Bl)[i * 256 + tid];

    for (int k = tid; k < 512; k += 256) {
      float t = 0.f, sg = 0.f, cc = -1.f;
      if (k < Kin) {
        float m  = (float)gs_in[k] * (1.0f / 16384.0f);
        float ms = (float)gq_in[k] * (1.0f / 16384.0f);
        float var = fmaxf(ms - m * m, 0.0f);
        float gv = a.g[li - 1][k], be = a.be[li - 1][k];
        if (gv != 0.0f) {
          t = m - be * sqrtf(var + 1e-5f) / gv;
          sg = (gv > 0.0f) ? 1.0f : -1.0f;
          cc = 0.0f;
        } else { t = 0.0f; sg = 0.0f; cc = be; }
      }
      thrbuf[k] = t; thrbuf[512 + k] = sg; thrbuf[1024 + k] = cc;
    }
#pragma unroll
    for (int i = 0; i < 8; i++) ((uint4*)Bsw)[i * 256 + tid] = bv[i];
    __syncthreads();   // thrbuf + Bsw visible

    int nacc[4][8];
#pragma unroll
    for (int r = 0; r < 4; r++)
#pragma unroll
      for (int j = 0; j < 8; j++) nacc[r][j] = 0;

#pragma unroll
    for (int c2 = 0; c2 < 2; c2++) {       // no syncs inside: all reads
      unsigned Aw[4][8];
#pragma unroll
      for (int cb = 0; cb < 4; cb++) {
        int k = c2 * 256 + (cb << 6) + lane;
        float t = thrbuf[k], sg = thrbuf[512 + k], cc = thrbuf[1024 + k];
#pragma unroll
        for (int r = 0; r < 4; r++) {
          bool p = (k < Kin) &&
                   ((((float)y[r][c2 * 4 + cb] - t) * sg + cc) >= 0.0f);
          unsigned long long m = __ballot(p);
          Aw[r][2 * cb]     = (unsigned)m;
          Aw[r][2 * cb + 1] = (unsigned)(m >> 32);
        }
      }
      const unsigned* B = Bsw + c2 * 4096;
#pragma unroll
      for (int w = 0; w < 8; w++) {
#pragma unroll
        for (int jj = 0; jj < 8; jj++) {
          unsigned bw = B[(w << 9) + (jj << 6) + lane];
#pragma unroll
          for (int r = 0; r < 4; r++)
            nacc[r][jj] += __popc(Aw[r][w] ^ bw);
        }
      }
    }
#pragma unroll
    for (int jj = 0; jj < 8; jj++) {
      int col = (jj << 6) + lane;
      int bsv = (col < Nout) ? bsl[col] : 0;
#pragma unroll
      for (int r = 0; r < 4; r++) {
        int v = Kin - 2 * nacc[r][jj] + bsv;
        y[r][jj] = v;
        if (final_layer && col < 35)
          a.out[(size_t)(row0 + wv * 4 + r) * 35 + col] = (float)v;
      }
    }
    if (!final_layer) {
      int* gs_out = a.gs + (size_t)li * 512;
      unsigned long long* gq_out = a.gq + (size_t)li * 512;
      __syncthreads();
      red_s[tid] = 0; red_s[tid + 256] = 0;
      red_q[tid] = 0; red_q[tid + 256] = 0;
      __syncthreads();
#pragma unroll
      for (int jj = 0; jj < 8; jj++) {
        int col = (jj << 6) + lane;
        if (col < Nout) {
          int s = 0, q = 0;
#pragma unroll
          for (int r = 0; r < 4; r++) { s += y[r][jj]; q += y[r][jj] * y[r][jj]; }
          atomicAdd(&red_s[col], s);
          atomicAdd(&red_q[col], q);
        }
      }
      __syncthreads();
      for (int c = tid; c < Nout; c += 256) {
        atomicAdd(&gs_out[c], red_s[c]);
        atomicAdd(&gq_out[c], (unsigned long long)(long long)red_q[c]);
      }
      gridbar(a.bar, ++ep);
    }
  }
}

// ===================== FALLBACK: proven round-1 pipeline =====================
struct PackArgs { const float* W[6]; const float* b[6]; };

__global__ __launch_bounds__(256) void fb_pack(PackArgs a, unsigned* B1, unsigned* By, int* bs)
{
  int blk = blockIdx.x;
  int l, n;
  if      (blk < 500)  { l = 0; n = blk; }
  else if (blk < 900)  { l = 1; n = blk - 500; }
  else if (blk < 1250) { l = 2; n = blk - 900; }
  else if (blk < 1550) { l = 3; n = blk - 1250; }
  else if (blk < 1850) { l = 4; n = blk - 1550; }
  else                 { l = 5; n = blk - 1850; }
  const int Ks[6] = {4096, 500, 400, 350, 300, 300};
  int K = Ks[l];
  int KW = (l == 0) ? 128 : 16;
  unsigned* Bout = (l == 0) ? B1 : (By + (size_t)(l - 1) * 512 * 16);
  const float* Wrow = a.W[l] + (size_t)n * K;
  int lane = threadIdx.x & 63;
  int wvv = threadIdx.x >> 6;
  for (int c = wvv; c < KW / 2; c += 4) {
    int k = c * 64 + lane;
    bool pred = (k < K) && (Wrow[k] >= 0.0f);
    unsigned long long m = __ballot(pred);
    if (lane == 0) {
      Bout[(size_t)n * KW + 2 * c]     = (unsigned)m;
      Bout[(size_t)n * KW + 2 * c + 1] = (unsigned)(m >> 32);
    }
  }
  if (threadIdx.x == 0) bs[l * 512 + n] = (a.b[l][n] >= 0.0f) ? 1 : -1;
}

__global__ __launch_bounds__(256) void fb_gemm1(const float* __restrict__ x,
    const unsigned* __restrict__ B1, const int* __restrict__ bs1,
    short* __restrict__ y1, int* __restrict__ gs, unsigned long long* __restrict__ gq)
{
  __shared__ __align__(16) unsigned Abits[32 * 128];
  __shared__ __align__(16) unsigned Bsw[256 * 32];
  __shared__ int red_s[256];
  __shared__ int red_q[256];
  int tid = threadIdx.x;
  int lane = tid & 63, wvv = tid >> 6;
  int cg2 = tid & 31, rg = tid >> 5;
  int row0 = blockIdx.x * 32;

  for (int i0 = wvv * 512; i0 < wvv * 512 + 512; i0 += 8) {
    int r = i0 >> 6;
    int cb = i0 & 63;
    const float* xp = x + (size_t)(row0 + r) * 4096 + cb * 64 + lane;
    float v[8];
#pragma unroll
    for (int u = 0; u < 8; u++) v[u] = xp[u * 64];
#pragma unroll
    for (int u = 0; u < 8; u++) {
      unsigned long long m = __ballot(v[u] >= 0.0f);
      if (lane == 0)
        *(unsigned long long*)&Abits[r * 128 + 2 * (cb + u)] = m;
    }
  }

  for (int pass = 0; pass < 2; pass++) {
    int colbase = pass * 256;
    unsigned acc[4][8];
#pragma unroll
    for (int r = 0; r < 4; r++)
#pragma unroll
      for (int j = 0; j < 8; j++) acc[r][j] = 0;

    for (int kc = 0; kc < 4; kc++) {
      __syncthreads();
#pragma unroll
      for (int i = 0; i < 8; i++) {
        int q = i * 256 + tid;
        int c = q >> 3;
        int w4 = (q & 7) << 2;
        uint4 bv = *(const uint4*)(B1 + (size_t)(colbase + c) * 128 + kc * 32 + w4);
        int g = (w4 >> 2) ^ (c & 7);
        *(uint4*)&Bsw[c * 32 + 4 * g] = bv;
      }
      __syncthreads();
#pragma unroll
      for (int w4 = 0; w4 < 32; w4 += 4) {
        uint4 av[4];
#pragma unroll
        for (int r = 0; r < 4; r++)
          av[r] = *(const uint4*)&Abits[(rg * 4 + r) * 128 + kc * 32 + w4];
#pragma unroll
        for (int jj = 0; jj < 8; jj++) {
          int c = jj * 32 + cg2;
          int g = (w4 >> 2) ^ (c & 7);
          uint4 bv = *(const uint4*)&Bsw[c * 32 + 4 * g];
#pragma unroll
          for (int r = 0; r < 4; r++)
            acc[r][jj] += __popc(av[r].x ^ bv.x) + __popc(av[r].y ^ bv.y)
                        + __popc(av[r].z ^ bv.z) + __popc(av[r].w ^ bv.w);
        }
      }
    }
    red_s[tid] = 0; red_q[tid] = 0;
    __syncthreads();
#pragma unroll
    for (int jj = 0; jj < 8; jj++) {
      int col = colbase + jj * 32 + cg2;
      int bsv = (col < 500) ? bs1[col] : 0;
      int s = 0, q = 0;
#pragma unroll
      for (int r = 0; r < 4; r++) {
        int yv = 4096 - 2 * (int)acc[r][jj] + bsv;
        if (col < 500)
          y1[(size_t)(row0 + rg * 4 + r) * 500 + col] = (short)yv;
        s += yv; q += yv * yv;
      }
      atomicAdd(&red_s[jj * 32 + cg2], s);
      atomicAdd(&red_q[jj * 32 + cg2], q);
    }
    __syncthreads();
    {
      int col = colbase + tid;
      if (col < 500) {
        atomicAdd(&gs[col], red_s[tid]);
        atomicAdd(&gq[col], (unsigned long long)(long long)red_q[tid]);
      }
    }
  }
}

__global__ __launch_bounds__(256) void fb_gemmy(
    const short* __restrict__ yin, int strin, int Kin,
    const int* __restrict__ gs_in, const unsigned long long* __restrict__ gq_in,
    const float* __restrict__ g_in, const float* __restrict__ be_in,
    const unsigned* __restrict__ Bb, const int* __restrict__ bsl,
    int Nout, int strout, int passes,
    short* __restrict__ yout, int* __restrict__ gs_out, unsigned long long* __restrict__ gq_out,
    float* __restrict__ fout, int is_final)
{
  __shared__ __align__(16) unsigned Abits[32 * 16];
  __shared__ __align__(16) unsigned Bsw[256 * 16];
  __shared__ float thr_t[512], thr_g[512], thr_c[512];
  __shared__ int red_s[256], red_q[256];
  int tid = threadIdx.x;
  int lane = tid & 63, wvv = tid >> 6;
  int cg2 = tid & 31, rg = tid >> 5;
  int row0 = blockIdx.x * 32;

  for (int k = tid; k < 512; k += 256) {
    float t = 0.f, sg = 0.f, cc = -1.f;
    if (k < Kin) {
      float m  = (float)gs_in[k] * (1.0f / 16384.0f);
      float ms = (float)gq_in[k] * (1.0f / 16384.0f);
      float var = fmaxf(ms - m * m, 0.0f);
      float g = g_in[k], be = be_in[k];
      if (g != 0.0f) {
        t = m - be * sqrtf(var + 1e-5f) / g;
        sg = (g > 0.0f) ? 1.0f : -1.0f;
        cc = 0.0f;
      } else { t = 0.0f; sg = 0.0f; cc = be; }
    }
    thr_t[k] = t; thr_g[k] = sg; thr_c[k] = cc;
  }
  __syncthreads();

  for (int i0 = wvv * 64; i0 < wvv * 64 + 64; i0 += 4) {
    int r = i0 >> 3;
    int cb = i0 & 7;
    const short* yp = yin + (size_t)(row0 + r) * strin;
    float v[4];
#pragma unroll
    for (int u = 0; u < 4; u++) {
      int k = (cb + u) * 64 + lane;
      v[u] = (k < Kin) ? (float)yp[k] : -1.0f;
    }
#pragma unroll
    for (int u = 0; u < 4; u++) {
      int k = (cb + u) * 64 + lane;
      bool p = (k < Kin) && (((v[u] - thr_t[k]) * thr_g[k] + thr_c[k]) >= 0.0f);
      unsigned long long m = __ballot(p);
      if (lane == 0)
        *(unsigned long long*)&Abits[r * 16 + 2 * (cb + u)] = m;
    }
  }

  for (int pass = 0; pass < passes; pass++) {
    int colbase = pass * 256;
    __syncthreads();
#pragma unroll
    for (int i = 0; i < 4; i++) {
      int q = i * 256 + tid;
      int c = q >> 2;
      int w4 = (q & 3) << 2;
      uint4 bv = *(const uint4*)(Bb + (size_t)(colbase + c) * 16 + w4);
      int g = (w4 >> 2) ^ (c & 3);
      *(uint4*)&Bsw[c * 16 + 4 * g] = bv;
    }
    __syncthreads();
    unsigned acc[4][8];
#pragma unroll
    for (int r = 0; r < 4; r++)
#pragma unroll
      for (int j = 0; j < 8; j++) acc[r][j] = 0;
#pragma unroll
    for (int w4 = 0; w4 < 4; w4++) {
      uint4 av[4];
#pragma unroll
      for (int r = 0; r < 4; r++)
        av[r] = *(const uint4*)&Abits[(rg * 4 + r) * 16 + w4 * 4];
#pragma unroll
      for (int jj = 0; jj < 8; jj++) {
        int c = jj * 32 + cg2;
        int g = (w4) ^ (c & 3);
        uint4 bv = *(const uint4*)&Bsw[c * 16 + 4 * g];
#pragma unroll
        for (int r = 0; r < 4; r++)
          acc[r][jj] += __popc(av[r].x ^ bv.x) + __popc(av[r].y ^ bv.y)
                      + __popc(av[r].z ^ bv.z) + __popc(av[r].w ^ bv.w);
      }
    }
    red_s[tid] = 0; red_q[tid] = 0;
    __syncthreads();
#pragma unroll
    for (int jj = 0; jj < 8; jj++) {
      int col = colbase + jj * 32 + cg2;
      int bsv = (col < Nout) ? bsl[col] : 0;
      int s = 0, q = 0;
#pragma unroll
      for (int r = 0; r < 4; r++) {
        int yv = Kin - 2 * (int)acc[r][jj] + bsv;
        if (col < Nout) {
          if (is_final) fout[(size_t)(row0 + rg * 4 + r) * Nout + col] = (float)yv;
          else          yout[(size_t)(row0 + rg * 4 + r) * strout + col] = (short)yv;
        }
        s += yv; q += yv * yv;
      }
      if (!is_final && col < Nout) {
        atomicAdd(&red_s[jj * 32 + cg2], s);
        atomicAdd(&red_q[jj * 32 + cg2], q);
      }
    }
    if (!is_final) {
      __syncthreads();
      int col = colbase + tid;
      if (col < Nout) {
        atomicAdd(&gs_out[col], red_s[tid]);
        atomicAdd(&gq_out[col], (unsigned long long)(long long)red_q[tid]);
      }
      __syncthreads();
    }
  }
}

// ================================ host ================================
extern "C" void kernel_launch(void* const* d_in, const int* in_sizes, int n_in,
                              void* d_out, int out_size, void* d_ws, size_t ws_size,
                              hipStream_t stream)
{
  (void)in_sizes; (void)n_in; (void)out_size; (void)ws_size;
  char* ws = (char*)d_ws;
  unsigned* Bt1 = (unsigned*)(ws);
  unsigned* ByT = (unsigned*)(ws + 262144);
  int* bs       = (int*)(ws + 425984);
  int* gs       = (int*)(ws + 438272);
  unsigned long long* gq = (unsigned long long*)(ws + 448512);
  unsigned* bar = (unsigned*)(ws + 469504);   // 2 cache lines: count / gen
  short* yA = (short*)(ws + 471040);
  short* yB = yA + (size_t)16384 * 512;

  Args ka;
  ka.x    = (const float*)d_in[0];
  ka.W[0] = (const float*)d_in[1];  ka.b[0] = (const float*)d_in[2];
  ka.W[1] = (const float*)d_in[5];  ka.b[1] = (const float*)d_in[6];
  ka.W[2] = (const float*)d_in[9];  ka.b[2] = (const float*)d_in[10];
  ka.W[3] = (const float*)d_in[13]; ka.b[3] = (const float*)d_in[14];
  ka.W[4] = (const float*)d_in[17]; ka.b[4] = (const float*)d_in[18];
  ka.W[5] = (const float*)d_in[21]; ka.b[5] = (const float*)d_in[22];
  ka.g[0] = (const float*)d_in[3];  ka.be[0] = (const float*)d_in[4];
  ka.g[1] = (const float*)d_in[7];  ka.be[1] = (const float*)d_in[8];
  ka.g[2] = (const float*)d_in[11]; ka.be[2] = (const float*)d_in[12];
  ka.g[3] = (const float*)d_in[15]; ka.be[3] = (const float*)d_in[16];
  ka.g[4] = (const float*)d_in[19]; ka.be[4] = (const float*)d_in[20];
  ka.out = (float*)d_out;
  ka.Bt1 = Bt1; ka.ByT = ByT; ka.bs = bs; ka.gs = gs; ka.gq = gq;
  ka.bar = bar;

  // Co-residency gate: need 4 blocks/CU on 256 CUs for the 1024-block grid.
  int maxPerCU = 0;
  hipError_t qerr = hipOccupancyMaxActiveBlocksPerMultiprocessor(
      &maxPerCU, reinterpret_cast<const void*>(&bnn_all), 256, 0);
  bool use_persist = (qerr == hipSuccess) && (maxPerCU >= 4);

  if (use_persist) {
    hipMemsetAsync(ws + 469504, 0, 256, stream);   // barrier count + gen = 0
    bnn_all<<<1024, 256, 0, stream>>>(ka);         // regular launch (no coop)
    return;
  }

  // -------- fallback: proven multi-kernel pipeline (round-1 structure) --------
  hipMemsetAsync(ws + 438272, 0, 30720, stream);  // zero stats

  PackArgs pa;
  for (int i = 0; i < 6; i++) { pa.W[i] = ka.W[i]; pa.b[i] = ka.b[i]; }

  fb_pack<<<1885, 256, 0, stream>>>(pa, Bt1, ByT, bs);
  fb_gemm1<<<512, 256, 0, stream>>>((const float*)d_in[0], Bt1, bs, yA, gs, gq);
  fb_gemmy<<<512, 256, 0, stream>>>(yA, 500, 500, gs, gq,
      ka.g[0], ka.be[0], ByT + 0 * 512 * 16, bs + 512, 400, 400, 2,
      yB, gs + 512, gq + 512, nullptr, 0);
  fb_gemmy<<<512, 256, 0, stream>>>(yB, 400, 400, gs + 512, gq + 512,
      ka.g[1], ka.be[1], ByT + 1 * 512 * 16, bs + 1024, 350, 352, 2,
      yA, gs + 1024, gq + 1024, nullptr, 0);
  fb_gemmy<<<512, 256, 0, stream>>>(yA, 352, 350, gs + 1024, gq + 1024,
      ka.g[2], ka.be[2], ByT + 2 * 512 * 16, bs + 1536, 300, 300, 2,
      yB, gs + 1536, gq + 1536, nullptr, 0);
  fb_gemmy<<<512, 256, 0, stream>>>(yB, 300, 300, gs + 1536, gq + 1536,
      ka.g[3], ka.be[3], ByT + 3 * 512 * 16, bs + 2048, 300, 300, 2,
      yA, gs + 2048, gq + 2048, nullptr, 0);
  fb_gemmy<<<512, 256, 0, stream>>>(yA, 300, 300, gs + 2048, gq + 2048,
      ka.g[4], ka.be[4], ByT + 4 * 512 * 16, bs + 2560, 35, 35, 1,
      nullptr, nullptr, nullptr, (float*)d_out, 1);
}

// Round 3
// 633.419 us; speedup vs baseline: 1.3864x; 1.3826x over previous
//
#include <hip/hip_runtime.h>

// ============================ shared arg struct ============================
struct Args {
  const float* x;
  const float* W[6];
  const float* b[6];
  const float* g[5];
  const float* be[5];
  float* out;
  unsigned* Bt1;            // [128 words][512 cols] layer-1 weight bits (transposed)
  unsigned* ByT;            // 5 x [16 words][512 cols]
  int* bs;                  // [6][512] bias signs (+1/-1)
  int* gs;                  // [5][512] col sums (int, exact)
  unsigned long long* gq;   // [5][512] col sumsq (u64, exact)
  unsigned* bar;            // barrier words: [0]=arrival count, [32]=generation
};

// ---- custom grid barrier: read-only polling, leader-only fences ----
// Arrival: one agent-scope fetch_add per block. Wait: read-only agent-scope
// polling of a generation word on a separate cache line + s_sleep backoff.
// Co-residency is guaranteed statically: __launch_bounds__(256,2) caps VGPR
// at 256 (2 waves/EU -> 2 blocks/CU) and LDS 38.9KB -> 2 blocks/CU; grid is
// 512 = 2 x 256 CUs. Host memsets bar to 0 before each launch.
__device__ __forceinline__ void gridbar(unsigned* bar, unsigned target)
{
  __syncthreads();                         // all block work done
  if (threadIdx.x == 0) {
    __threadfence();                       // release: write back dirty L2
    unsigned prev = __hip_atomic_fetch_add(&bar[0], 1u, __ATOMIC_RELAXED,
                                           __HIP_MEMORY_SCOPE_AGENT);
    if (prev == gridDim.x - 1) {           // last arriver
      __hip_atomic_store(&bar[0], 0u, __ATOMIC_RELAXED,
                         __HIP_MEMORY_SCOPE_AGENT);
      __hip_atomic_store(&bar[32], target, __ATOMIC_RELEASE,
                         __HIP_MEMORY_SCOPE_AGENT);
    } else {
      while (__hip_atomic_load(&bar[32], __ATOMIC_RELAXED,
                               __HIP_MEMORY_SCOPE_AGENT) < target)
        __builtin_amdgcn_s_sleep(2);       // ~0.1us poll period, read-only
    }
    __threadfence();                       // acquire: invalidate stale L2
  }
  __syncthreads();
}

// ===================== THE kernel: one persistent grid =====================
// 512 blocks x 256 thr (2/CU, 8 waves/CU), 32 rows/block resident for the
// whole net. Thread (wave wv, lane) holds y[r][jj] = row row0+wv*8+r, col
// jj*64+lane in regs. r=8 so each LDS B-word read amortizes over 8 popc rows
// (VALU-dominant; r=4 in round 2 was LDS-pipe-bound). Layer 1 software-
// pipelined: x chunk kc+1 prefetched into regs during popc of kc; B tiles
// double-buffered in 32KB LDS, ONE __syncthreads per chunk (stage-loads
// early, ds_writes after popc). Ballot A-bits live in SGPRs (wave-uniform).
// Exact-int BN stats; 6 read-only-spin grid barriers.
__global__ __launch_bounds__(256, 2) void bnn_all(Args a)
{
  __shared__ __align__(16) unsigned Bsw[16 * 512];   // 32 KB: L1 dbuf / whole ByT layer
  __shared__ __align__(16) float thrbuf[1536];       // 6 KB; aliased by red_s/red_q
  int* red_s = (int*)thrbuf;
  int* red_q = red_s + 512;

  const int tid = threadIdx.x;
  const int lane = tid & 63;
  const int wv = tid >> 6;
  const int row0 = blockIdx.x * 32;
  int ep = 0;                              // barrier epoch (uniform control flow)

  // ---------- phase 0: zero stats + pack weight/bias sign bits ----------
  {
    int idx = blockIdx.x * 256 + tid;
    if (idx < 7680) ((int*)a.gs)[idx] = 0;   // gs(10240B)+gq(20480B) contiguous
  }
  for (int R = blockIdx.x; R < 1885; R += 512) {
    int l, n;
    if      (R < 500)  { l = 0; n = R; }
    else if (R < 900)  { l = 1; n = R - 500; }
    else if (R < 1250) { l = 2; n = R - 900; }
    else if (R < 1550) { l = 3; n = R - 1250; }
    else if (R < 1850) { l = 4; n = R - 1550; }
    else               { l = 5; n = R - 1850; }
    const int Ks[6] = {4096, 500, 400, 350, 300, 300};
    int K = Ks[l];
    int chunks = (l == 0) ? 64 : 8;
    unsigned* Bout = (l == 0) ? a.Bt1 : (a.ByT + (size_t)(l - 1) * 16 * 512);
    const float* Wrow = a.W[l] + (size_t)n * K;
    for (int c = wv; c < chunks; c += 4) {
      int k = c * 64 + lane;
      bool pred = (k < K) && (Wrow[k] >= 0.0f);
      unsigned long long m = __ballot(pred);
      if (lane == 0) {
        Bout[(size_t)(2 * c) * 512 + n]     = (unsigned)m;
        Bout[(size_t)(2 * c + 1) * 512 + n] = (unsigned)(m >> 32);
      }
    }
    if (tid == 0) a.bs[l * 512 + n] = (a.b[l][n] >= 0.0f) ? 1 : -1;
  }

  // prefetch x chunk kc=0 into regs BEFORE the barrier (hides under barrier wait)
  const float* xbase = a.x + (size_t)(row0 + wv * 8) * 4096 + lane;
  float xv[8][4];
#pragma unroll
  for (int r = 0; r < 8; r++)
#pragma unroll
    for (int cb = 0; cb < 4; cb++)
      xv[r][cb] = xbase[(size_t)r * 4096 + cb * 64];

  gridbar(a.bar, ++ep);

  // ---------- layer 1: x read once -> y[8][8] registers ----------
  // prologue: stage B chunk 0 into buf0 (Bt1 valid only after the barrier)
  {
    const uint4* src = (const uint4*)a.Bt1;
#pragma unroll
    for (int i = 0; i < 4; i++)
      ((uint4*)Bsw)[i * 256 + tid] = src[i * 256 + tid];
  }

  int y[8][8];
#pragma unroll
  for (int r = 0; r < 8; r++)
#pragma unroll
    for (int j = 0; j < 8; j++) y[r][j] = 0;

  for (int kc = 0; kc < 16; kc++) {        // 16 chunks of 256 K-bits (8 words)
    // ballots from prefetched xv -> Aw in SGPRs (wave-uniform)
    unsigned Aw[8][8];
#pragma unroll
    for (int r = 0; r < 8; r++)
#pragma unroll
      for (int cb = 0; cb < 4; cb++) {
        unsigned long long m = __ballot(xv[r][cb] >= 0.0f);
        Aw[r][2 * cb]     = (unsigned)m;
        Aw[r][2 * cb + 1] = (unsigned)(m >> 32);
      }
    // prefetch x chunk kc+1 (WAR on xv: issued after ballots consume regs)
    if (kc < 15) {
#pragma unroll
      for (int r = 0; r < 8; r++)
#pragma unroll
        for (int cb = 0; cb < 4; cb++)
          xv[r][cb] = xbase[(size_t)r * 4096 + (kc + 1) * 256 + cb * 64];
    }
    __syncthreads();   // buf[kc&1] fully staged (prev iter's post-popc writes)
    // stage-loads for kc+1 issue now; ds_writes deferred to after popc (T14)
    uint4 sbuf[4];
    if (kc < 15) {
      const uint4* src = (const uint4*)(a.Bt1 + (size_t)(kc + 1) * 4096);
#pragma unroll
      for (int i = 0; i < 4; i++) sbuf[i] = src[i * 256 + tid];
    }
    const unsigned* B = Bsw + (kc & 1) * 4096;
#pragma unroll
    for (int w = 0; w < 8; w++) {
#pragma unroll
      for (int jj = 0; jj < 8; jj++) {
        unsigned bw = B[(w << 9) + (jj << 6) + lane];
#pragma unroll
        for (int r = 0; r < 8; r++)
          y[r][jj] += __popc(Aw[r][w] ^ bw);
      }
    }
    if (kc < 15) {
      uint4* dst = (uint4*)Bsw + (size_t)((kc + 1) & 1) * 1024;
#pragma unroll
      for (int i = 0; i < 4; i++) dst[i * 256 + tid] = sbuf[i];
    }
  }
#pragma unroll
  for (int jj = 0; jj < 8; jj++) {
    int col = (jj << 6) + lane;
    int bsv = (col < 500) ? a.bs[col] : 0;
#pragma unroll
    for (int r = 0; r < 8; r++) y[r][jj] = 4096 - 2 * y[r][jj] + bsv;
  }
  // layer-1 stats (slot 0)
  {
    __syncthreads();
    red_s[tid] = 0; red_s[tid + 256] = 0;
    red_q[tid] = 0; red_q[tid + 256] = 0;
    __syncthreads();
#pragma unroll
    for (int jj = 0; jj < 8; jj++) {
      int col = (jj << 6) + lane;
      if (col < 500) {
        int s = 0, q = 0;
#pragma unroll
        for (int r = 0; r < 8; r++) { s += y[r][jj]; q += y[r][jj] * y[r][jj]; }
        atomicAdd(&red_s[col], s);
        atomicAdd(&red_q[col], q);   // per-block <= 32*4097^2 < 2^31
      }
    }
    __syncthreads();
    for (int c = tid; c < 500; c += 256) {
      atomicAdd(&a.gs[c], red_s[c]);
      atomicAdd(&a.gq[c], (unsigned long long)(long long)red_q[c]);
    }
    gridbar(a.bar, ++ep);
  }

  // ---------- layers 2..6 ----------
  const int Kins[5]  = {500, 400, 350, 300, 300};
  const int Nouts[5] = {400, 350, 300, 300, 35};
#pragma unroll 1
  for (int li = 1; li <= 5; li++) {
    const int Kin  = Kins[li - 1];
    const int Nout = Nouts[li - 1];
    const bool final_layer = (li == 5);
    const int* gs_in = a.gs + (size_t)(li - 1) * 512;
    const unsigned long long* gq_in = a.gq + (size_t)(li - 1) * 512;
    const unsigned* Bl = a.ByT + (size_t)(li - 1) * 16 * 512;
    const int* bsl = a.bs + (size_t)li * 512;

    __syncthreads();   // prev epilogue LDS reads done before thrbuf/Bsw rewrite
    // stage whole 32KB B-slice: loads issue now, overlap the BN-threshold math
    uint4 bv[8];
#pragma unroll
    for (int i = 0; i < 8; i++) bv[i] = ((const uint4*)Bl)[i * 256 + tid];

    for (int k = tid; k < 512; k += 256) {
      float t = 0.f, sg = 0.f, cc = -1.f;
      if (k < Kin) {
        float m  = (float)gs_in[k] * (1.0f / 16384.0f);
        float ms = (float)gq_in[k] * (1.0f / 16384.0f);
        float var = fmaxf(ms - m * m, 0.0f);
        float gv = a.g[li - 1][k], be = a.be[li - 1][k];
        if (gv != 0.0f) {
          t = m - be * sqrtf(var + 1e-5f) / gv;
          sg = (gv > 0.0f) ? 1.0f : -1.0f;
          cc = 0.0f;
        } else { t = 0.0f; sg = 0.0f; cc = be; }
      }
      thrbuf[k] = t; thrbuf[512 + k] = sg; thrbuf[1024 + k] = cc;
    }
#pragma unroll
    for (int i = 0; i < 8; i++) ((uint4*)Bsw)[i * 256 + tid] = bv[i];
    __syncthreads();   // thrbuf + Bsw visible

    int nacc[8][8];
#pragma unroll
    for (int r = 0; r < 8; r++)
#pragma unroll
      for (int j = 0; j < 8; j++) nacc[r][j] = 0;

#pragma unroll
    for (int c2 = 0; c2 < 2; c2++) {       // no syncs inside: all reads
      unsigned Aw[8][8];
#pragma unroll
      for (int cb = 0; cb < 4; cb++) {
        int k = c2 * 256 + (cb << 6) + lane;
        float t = thrbuf[k], sg = thrbuf[512 + k], cc = thrbuf[1024 + k];
#pragma unroll
        for (int r = 0; r < 8; r++) {
          bool p = (k < Kin) &&
                   ((((float)y[r][c2 * 4 + cb] - t) * sg + cc) >= 0.0f);
          unsigned long long m = __ballot(p);
          Aw[r][2 * cb]     = (unsigned)m;
          Aw[r][2 * cb + 1] = (unsigned)(m >> 32);
        }
      }
      const unsigned* B = Bsw + c2 * 4096;
#pragma unroll
      for (int w = 0; w < 8; w++) {
#pragma unroll
        for (int jj = 0; jj < 8; jj++) {
          unsigned bw = B[(w << 9) + (jj << 6) + lane];
#pragma unroll
          for (int r = 0; r < 8; r++)
            nacc[r][jj] += __popc(Aw[r][w] ^ bw);
        }
      }
    }
#pragma unroll
    for (int jj = 0; jj < 8; jj++) {
      int col = (jj << 6) + lane;
      int bsv = (col < Nout) ? bsl[col] : 0;
#pragma unroll
      for (int r = 0; r < 8; r++) {
        int v = Kin - 2 * nacc[r][jj] + bsv;
        y[r][jj] = v;
        if (final_layer && col < 35)
          a.out[(size_t)(row0 + wv * 8 + r) * 35 + col] = (float)v;
      }
    }
    if (!final_layer) {
      int* gs_out = a.gs + (size_t)li * 512;
      unsigned long long* gq_out = a.gq + (size_t)li * 512;
      __syncthreads();
      red_s[tid] = 0; red_s[tid + 256] = 0;
      red_q[tid] = 0; red_q[tid + 256] = 0;
      __syncthreads();
#pragma unroll
      for (int jj = 0; jj < 8; jj++) {
        int col = (jj << 6) + lane;
        if (col < Nout) {
          int s = 0, q = 0;
#pragma unroll
          for (int r = 0; r < 8; r++) { s += y[r][jj]; q += y[r][jj] * y[r][jj]; }
          atomicAdd(&red_s[col], s);
          atomicAdd(&red_q[col], q);
        }
      }
      __syncthreads();
      for (int c = tid; c < Nout; c += 256) {
        atomicAdd(&gs_out[c], red_s[c]);
        atomicAdd(&gq_out[c], (unsigned long long)(long long)red_q[c]);
      }
      gridbar(a.bar, ++ep);
    }
  }
}

// ================================ host ================================
// Single unambiguous path: no occupancy gate, no fallback. Co-residency of
// 512 blocks (2/CU x 256 CUs) is statically guaranteed by __launch_bounds__
// (256,2) [VGPR cap 256 -> 2 waves/EU] and LDS 38.9KB [-> 4/CU by LDS].
extern "C" void kernel_launch(void* const* d_in, const int* in_sizes, int n_in,
                              void* d_out, int out_size, void* d_ws, size_t ws_size,
                              hipStream_t stream)
{
  (void)in_sizes; (void)n_in; (void)out_size; (void)ws_size;
  char* ws = (char*)d_ws;
  unsigned* Bt1 = (unsigned*)(ws);
  unsigned* ByT = (unsigned*)(ws + 262144);
  int* bs       = (int*)(ws + 425984);
  int* gs       = (int*)(ws + 438272);
  unsigned long long* gq = (unsigned long long*)(ws + 448512);
  unsigned* bar = (unsigned*)(ws + 469504);   // 2 cache lines: count / gen

  Args ka;
  ka.x    = (const float*)d_in[0];
  ka.W[0] = (const float*)d_in[1];  ka.b[0] = (const float*)d_in[2];
  ka.W[1] = (const float*)d_in[5];  ka.b[1] = (const float*)d_in[6];
  ka.W[2] = (const float*)d_in[9];  ka.b[2] = (const float*)d_in[10];
  ka.W[3] = (const float*)d_in[13]; ka.b[3] = (const float*)d_in[14];
  ka.W[4] = (const float*)d_in[17]; ka.b[4] = (const float*)d_in[18];
  ka.W[5] = (const float*)d_in[21]; ka.b[5] = (const float*)d_in[22];
  ka.g[0] = (const float*)d_in[3];  ka.be[0] = (const float*)d_in[4];
  ka.g[1] = (const float*)d_in[7];  ka.be[1] = (const float*)d_in[8];
  ka.g[2] = (const float*)d_in[11]; ka.be[2] = (const float*)d_in[12];
  ka.g[3] = (const float*)d_in[15]; ka.be[3] = (const float*)d_in[16];
  ka.g[4] = (const float*)d_in[19]; ka.be[4] = (const float*)d_in[20];
  ka.out = (float*)d_out;
  ka.Bt1 = Bt1; ka.ByT = ByT; ka.bs = bs; ka.gs = gs; ka.gq = gq;
  ka.bar = bar;

  hipMemsetAsync(ws + 469504, 0, 256, stream);   // barrier count + gen = 0
  bnn_all<<<512, 256, 0, stream>>>(ka);
}